// Round 1
// baseline (1053.295 us; speedup 1.0000x reference)
//
#include <hip/hip_runtime.h>

#define C_DIM 128
#define H_DIM 256
#define L_NUM 4

typedef __attribute__((ext_vector_type(8))) short bf16x8;
typedef __attribute__((ext_vector_type(4))) float f32x4;

__device__ __forceinline__ unsigned short f2bf(float f){
  unsigned u = __builtin_bit_cast(unsigned, f);
  u = u + 0x7FFFu + ((u >> 16) & 1u);   // round-to-nearest-even
  return (unsigned short)(u >> 16);
}

// ---------------- CSR build ----------------
__global__ void k_hist(const int* __restrict__ dst, int* __restrict__ cnt, int E){
  for (int e = blockIdx.x*blockDim.x + threadIdx.x; e < E; e += gridDim.x*blockDim.x)
    atomicAdd(cnt + dst[e], 1);
}

__global__ void k_scan_local(const int* __restrict__ cnt, int* __restrict__ rp,
                             int* __restrict__ bsum, int N){
  __shared__ int tmp[256];
  int t = threadIdx.x; int i = blockIdx.x*256 + t;
  int v = (i < N) ? cnt[i] : 0;
  tmp[t] = v; __syncthreads();
  for (int off = 1; off < 256; off <<= 1){
    int x = (t >= off) ? tmp[t-off] : 0; __syncthreads();
    tmp[t] += x; __syncthreads();
  }
  if (i < N) rp[i] = tmp[t] - v;              // exclusive within block
  if (t == 255) bsum[blockIdx.x] = tmp[t];
}

__global__ void k_scan_bsums(const int* __restrict__ bsum, int* __restrict__ boff, int nb){
  __shared__ int tmp[256];
  int t = threadIdx.x;
  int v = (t < nb) ? bsum[t] : 0;
  tmp[t] = v; __syncthreads();
  for (int off = 1; off < 256; off <<= 1){
    int x = (t >= off) ? tmp[t-off] : 0; __syncthreads();
    tmp[t] += x; __syncthreads();
  }
  if (t < nb) boff[t] = tmp[t] - v;           // exclusive
}

__global__ void k_scan_add(int* __restrict__ rp, const int* __restrict__ boff, int N, int E){
  int i = blockIdx.x*256 + threadIdx.x;
  if (i < N) rp[i] += boff[blockIdx.x];
  if (i == 0) rp[N] = E;
}

__global__ void k_scatter(const int* __restrict__ src, const int* __restrict__ dst,
                          const int* __restrict__ rp, int* __restrict__ cnt,
                          int* __restrict__ csrc, int E){
  for (int e = blockIdx.x*blockDim.x + threadIdx.x; e < E; e += gridDim.x*blockDim.x){
    int d = dst[e];
    int pos = rp[d] + atomicAdd(cnt + d, 1);
    csrc[pos] = src[e];
  }
}

// ---------------- weight transpose+convert ----------------
// W1 [L][128][256] -> W1t [L][256][128] bf16 ; W2 [L][256][128] -> W2t [L][128][256] bf16
__global__ void k_wconv(const float* __restrict__ W1, const float* __restrict__ W2,
                        unsigned short* __restrict__ W1t, unsigned short* __restrict__ W2t){
  int i = blockIdx.x*blockDim.x + threadIdx.x;
  if (i >= L_NUM*C_DIM*H_DIM) return;
  int l = i >> 15, r = i & 32767;
  { int k = r >> 8, n = r & 255;  W1t[l*32768 + n*128 + k] = f2bf(W1[i]); }
  { int k = r >> 7, n = r & 127;  W2t[l*32768 + n*256 + k] = f2bf(W2[i]); }
}

// ---------------- graph norm ----------------
__global__ void k_gn_reduce(const float* __restrict__ X, float* __restrict__ st, int N){
  int t = threadIdx.x; int c = t & 127; int half = t >> 7;
  float s = 0.f, s2 = 0.f;
  for (int r = blockIdx.x*2 + half; r < N; r += gridDim.x*2){
    float v = X[r*C_DIM + c]; s += v; s2 += v*v;
  }
  __shared__ float a1[256], a2[256];
  a1[t] = s; a2[t] = s2; __syncthreads();
  if (t < 128){
    atomicAdd(st + c, a1[t] + a1[t+128]);
    atomicAdd(st + 128 + c, a2[t] + a2[t+128]);
  }
}

__global__ void k_gn_coef(const float* __restrict__ st, const float* __restrict__ gw,
                          const float* __restrict__ gb, const float* __restrict__ ga,
                          float* __restrict__ coef, int N){
  int c = threadIdx.x;
  if (c >= 128) return;
  float inv = 1.f/(float)N;
  float mean = st[c]*inv;
  float am = ga[c]*mean;
  float var = st[128+c]*inv - 2.f*am*mean + am*am;   // E[(x - a*mean)^2]
  float scale = gw[c] * rsqrtf(var + 1e-5f);
  coef[c] = scale;
  coef[128+c] = gb[c] - scale*am;
}

__global__ void k_gn_apply(const float* __restrict__ X, const float* __restrict__ coef,
                           float* __restrict__ G, int total4){
  int i = blockIdx.x*blockDim.x + threadIdx.x;
  if (i >= total4) return;
  int c4 = i & 31;
  float4 x = ((const float4*)X)[i];
  float4 A = ((const float4*)coef)[c4];
  float4 B = ((const float4*)coef)[32 + c4];
  float4 o;
  o.x = fmaxf(A.x*x.x + B.x, 0.f);
  o.y = fmaxf(A.y*x.y + B.y, 0.f);
  o.z = fmaxf(A.z*x.z + B.z, 0.f);
  o.w = fmaxf(A.w*x.w + B.w, 0.f);
  ((float4*)G)[i] = o;
}

// ---------------- softmax aggregation (one wave per node, online) ----------------
// assumes t > 0 and g >= 0 so z = t*(g+eps) > 0 (init max = 0 is safe)
__global__ void k_agg(const float* __restrict__ g, const int* __restrict__ rp,
                      const int* __restrict__ csrc, const float* __restrict__ tptr, int l,
                      unsigned short* __restrict__ U, int N){
  int wave = threadIdx.x >> 6, lane = threadIdx.x & 63;
  int n = blockIdx.x*4 + wave;
  if (n >= N) return;
  float tv = tptr[l];
  int jb = rp[n], je = rp[n+1];
  int c = lane*2;
  float m0 = 0.f, m1 = 0.f, d0 = 0.f, d1 = 0.f, s0 = 0.f, s1 = 0.f;
  for (int j = jb; j < je; ++j){
    int sidx = csrc[j];
    float2 v = *(const float2*)(g + sidx*C_DIM + c);
    float msg0 = v.x + 1e-7f;           // relu(g)=g since g>=0
    float msg1 = v.y + 1e-7f;
    float z0 = tv*msg0, z1 = tv*msg1;
    float nm0 = fmaxf(m0, z0), nm1 = fmaxf(m1, z1);
    float e0 = __expf(z0 - nm0), r0 = __expf(m0 - nm0);
    float e1 = __expf(z1 - nm1), r1 = __expf(m1 - nm1);
    d0 = d0*r0 + e0;            d1 = d1*r1 + e1;
    s0 = s0*r0 + msg0*e0;       s1 = s1*r1 + msg1*e1;
    m0 = nm0; m1 = nm1;
  }
  float2 gown = *(const float2*)(g + n*C_DIM + c);
  float u0 = s0/(d0 + 1e-16f) + gown.x;
  float u1 = s1/(d1 + 1e-16f) + gown.y;
  unsigned pk = (unsigned)f2bf(u0) | ((unsigned)f2bf(u1) << 16);
  *(unsigned*)(U + n*C_DIM + c) = pk;
}

// ---------------- GEMM1: h1 = U(bf16)[M,128] @ W1t^T + b1 ; + global sum/sumsq ----------------
__global__ void k_gemm1(const unsigned short* __restrict__ A, const unsigned short* __restrict__ Bt,
                        const float* __restrict__ b1, float* __restrict__ H1,
                        float* __restrict__ red, int M){
  __shared__ __align__(16) char smem[64*256];   // 64 rows x 128 bf16 (256B rows), swizzled
  const int tid = threadIdx.x;
  const int m0 = blockIdx.x * 64;
  const int wave = tid >> 6, lane = tid & 63;
  const int lr = lane & 15, lc = lane >> 4;

  // B fragments (global, L2-resident): wave covers cols [wave*64, wave*64+64)
  bf16x8 bf[4][4];
  #pragma unroll
  for (int nf = 0; nf < 4; ++nf){
    int n = wave*64 + nf*16 + lr;
    #pragma unroll
    for (int ks = 0; ks < 4; ++ks)
      bf[nf][ks] = *(const bf16x8*)(Bt + n*128 + ks*32 + lc*8);
  }
  // stage A tile
  #pragma unroll
  for (int p = 0; p < 4; ++p){
    int idx = p*256 + tid;
    int row = idx >> 4, ch = idx & 15;
    int r = m0 + row;
    uint4 v = make_uint4(0u,0u,0u,0u);
    if (r < M) v = *(const uint4*)(A + r*128 + ch*8);
    int o = (row*256 + ch*16) ^ ((row & 7) << 4);
    *(uint4*)(smem + o) = v;
  }
  __syncthreads();

  f32x4 acc[4][4] = {};
  #pragma unroll
  for (int ks = 0; ks < 4; ++ks){
    bf16x8 a[4];
    #pragma unroll
    for (int mf = 0; mf < 4; ++mf){
      int row = mf*16 + lr;
      int o = (row*256 + ks*64 + lc*16) ^ ((row & 7) << 4);
      a[mf] = *(const bf16x8*)(smem + o);
    }
    #pragma unroll
    for (int mf = 0; mf < 4; ++mf)
      #pragma unroll
      for (int nf = 0; nf < 4; ++nf)
        acc[mf][nf] = __builtin_amdgcn_mfma_f32_16x16x32_bf16(a[mf], bf[nf][ks], acc[mf][nf], 0, 0, 0);
  }

  float s1 = 0.f, s2 = 0.f;
  #pragma unroll
  for (int mf = 0; mf < 4; ++mf){
    #pragma unroll
    for (int j = 0; j < 4; ++j){
      int r = m0 + mf*16 + lc*4 + j;
      if (r < M){
        #pragma unroll
        for (int nf = 0; nf < 4; ++nf){
          int col = wave*64 + nf*16 + lr;
          float v = acc[mf][nf][j] + b1[col];
          H1[r*H_DIM + col] = v;
          s1 += v; s2 += v*v;
        }
      }
    }
  }
  #pragma unroll
  for (int o = 32; o; o >>= 1){ s1 += __shfl_down(s1, o); s2 += __shfl_down(s2, o); }
  if (lane == 0){ atomicAdd(red, s1); atomicAdd(red + 1, s2); }
}

__global__ void k_ln_coef(const float* __restrict__ red, const float* __restrict__ lnw,
                          const float* __restrict__ lnb, float* __restrict__ coef, int M){
  int c = threadIdx.x;
  if (c >= 256) return;
  double NH = (double)M * (double)H_DIM;
  double mean = (double)red[0] / NH;
  double var = (double)red[1] / NH - mean*mean;
  double sd = sqrt(var > 0.0 ? var : 0.0);
  float denom = (float)sd + 1e-5f;
  float wv = lnw[c] / denom;
  coef[c] = wv;
  coef[256 + c] = lnb[c] - (float)mean * wv;
}

// ---------------- GEMM2: x += relu(affine(H1))(bf16) @ W2t^T + b2 ----------------
__global__ void k_gemm2(const float* __restrict__ H1, const float* __restrict__ lncoef,
                        const unsigned short* __restrict__ Bt, const float* __restrict__ b2,
                        float* __restrict__ X, int M){
  __shared__ __align__(16) char smem[64*512];   // 64 rows x 256 bf16 (512B rows), swizzled
  const int tid = threadIdx.x;
  const int m0 = blockIdx.x * 64;
  const int wave = tid >> 6, lane = tid & 63;
  const int lr = lane & 15, lc = lane >> 4;
  const float* colw = lncoef;
  const float* colb = lncoef + 256;

  bf16x8 bf[2][8];
  #pragma unroll
  for (int nf = 0; nf < 2; ++nf){
    int n = wave*32 + nf*16 + lr;
    #pragma unroll
    for (int ks = 0; ks < 8; ++ks)
      bf[nf][ks] = *(const bf16x8*)(Bt + n*256 + ks*32 + lc*8);
  }
  #pragma unroll
  for (int p = 0; p < 16; ++p){
    int idx = (p*256 + tid)*4;
    int row = idx >> 8, col = idx & 255;
    int r = m0 + row;
    float4 v = make_float4(0.f,0.f,0.f,0.f);
    if (r < M) v = *(const float4*)(H1 + r*H_DIM + col);
    float4 cw = *(const float4*)(colw + col);
    float4 cb = *(const float4*)(colb + col);
    unsigned short h0 = f2bf(fmaxf(cw.x*v.x + cb.x, 0.f));
    unsigned short h1v = f2bf(fmaxf(cw.y*v.y + cb.y, 0.f));
    unsigned short h2 = f2bf(fmaxf(cw.z*v.z + cb.z, 0.f));
    unsigned short h3 = f2bf(fmaxf(cw.w*v.w + cb.w, 0.f));
    uint2 pk = make_uint2((unsigned)h0 | ((unsigned)h1v << 16),
                          (unsigned)h2 | ((unsigned)h3 << 16));
    int o = (row*512 + col*2) ^ ((row & 7) << 4);
    *(uint2*)(smem + o) = pk;
  }
  __syncthreads();

  f32x4 acc[4][2] = {};
  #pragma unroll
  for (int ks = 0; ks < 8; ++ks){
    bf16x8 a[4];
    #pragma unroll
    for (int mf = 0; mf < 4; ++mf){
      int row = mf*16 + lr;
      int o = (row*512 + ks*64 + lc*16) ^ ((row & 7) << 4);
      a[mf] = *(const bf16x8*)(smem + o);
    }
    #pragma unroll
    for (int mf = 0; mf < 4; ++mf)
      #pragma unroll
      for (int nf = 0; nf < 2; ++nf)
        acc[mf][nf] = __builtin_amdgcn_mfma_f32_16x16x32_bf16(a[mf], bf[nf][ks], acc[mf][nf], 0, 0, 0);
  }
  #pragma unroll
  for (int mf = 0; mf < 4; ++mf){
    #pragma unroll
    for (int j = 0; j < 4; ++j){
      int r = m0 + mf*16 + lc*4 + j;
      if (r < M){
        #pragma unroll
        for (int nf = 0; nf < 2; ++nf){
          int col = wave*32 + nf*16 + lr;
          X[r*C_DIM + col] += acc[mf][nf][j] + b2[col];
        }
      }
    }
  }
}

// ---------------- final linear ----------------
__global__ void k_final(const float* __restrict__ X, const float* __restrict__ lw,
                        const float* __restrict__ lb, float* __restrict__ out, int N){
  int wave = threadIdx.x >> 6, lane = threadIdx.x & 63;
  int n = blockIdx.x*4 + wave;
  if (n >= N) return;
  float2 v = *(const float2*)(X + n*C_DIM + lane*2);
  float2 w = *(const float2*)(lw + lane*2);
  float s = v.x*w.x + v.y*w.y;
  #pragma unroll
  for (int o = 32; o; o >>= 1) s += __shfl_down(s, o);
  if (lane == 0) out[n] = s + lb[0];
}

extern "C" void kernel_launch(void* const* d_in, const int* in_sizes, int n_in,
                              void* d_out, int out_size, void* d_ws, size_t ws_size,
                              hipStream_t stream){
  const float* x    = (const float*)d_in[0];
  const int*   src  = (const int*)d_in[1];
  const int*   dst  = (const int*)d_in[2];
  const float* W1   = (const float*)d_in[3];
  const float* b1   = (const float*)d_in[4];
  const float* lnw  = (const float*)d_in[5];
  const float* lnb  = (const float*)d_in[6];
  const float* W2   = (const float*)d_in[7];
  const float* b2   = (const float*)d_in[8];
  const float* tpt  = (const float*)d_in[9];
  const float* gnw  = (const float*)d_in[10];
  const float* gnb  = (const float*)d_in[11];
  const float* gna  = (const float*)d_in[12];
  const float* linw = (const float*)d_in[13];
  const float* linb = (const float*)d_in[14];
  (void)n_in; (void)out_size; (void)ws_size;
  const int N = in_sizes[0] / C_DIM;
  const int E = in_sizes[1];
  float* out = (float*)d_out;

  char* wsp = (char*)d_ws; size_t off = 0;
  auto alloc = [&](size_t b)->char*{ char* p = wsp + off; off += (b + 255) & ~(size_t)255; return p; };
  int* cnt          = (int*)alloc((size_t)N*4);
  int* rp           = (int*)alloc((size_t)(N+1)*4);
  int* bsum         = (int*)alloc(1024);
  int* boff         = (int*)alloc(1024);
  float* stats      = (float*)alloc(2048);   // chsum[128], chsumsq[128], lnred[2]
  float* gncoef     = (float*)alloc(1024);
  float* lncoef     = (float*)alloc(2048);
  int* csrc         = (int*)alloc((size_t)E*4);
  unsigned short* W1t = (unsigned short*)alloc((size_t)L_NUM*C_DIM*H_DIM*2);
  unsigned short* W2t = (unsigned short*)alloc((size_t)L_NUM*C_DIM*H_DIM*2);
  float* g          = (float*)alloc((size_t)N*C_DIM*4);
  unsigned short* U = (unsigned short*)alloc((size_t)N*C_DIM*2);
  float* h1         = (float*)alloc((size_t)N*H_DIM*4);
  float* xc         = (float*)alloc((size_t)N*C_DIM*4);

  const int SB = (N + 255)/256;   // 196 blocks (<=256 required by scan)
  hipMemsetAsync(cnt, 0, (size_t)N*4, stream);
  k_hist<<<1024, 256, 0, stream>>>(dst, cnt, E);
  k_scan_local<<<SB, 256, 0, stream>>>(cnt, rp, bsum, N);
  k_scan_bsums<<<1, 256, 0, stream>>>(bsum, boff, SB);
  k_scan_add<<<SB, 256, 0, stream>>>(rp, boff, N, E);
  hipMemsetAsync(cnt, 0, (size_t)N*4, stream);
  k_scatter<<<1024, 256, 0, stream>>>(src, dst, rp, cnt, csrc, E);
  k_wconv<<<(L_NUM*C_DIM*H_DIM + 255)/256, 256, 0, stream>>>(W1, W2, W1t, W2t);
  hipMemcpyAsync(xc, x, (size_t)N*C_DIM*4, hipMemcpyDeviceToDevice, stream);

  const int gmw = (N + 63)/64;
  for (int l = 0; l < L_NUM; ++l){
    hipMemsetAsync(stats, 0, 2048, stream);
    k_gn_reduce<<<256, 256, 0, stream>>>(xc, stats, N);
    k_gn_coef<<<1, 128, 0, stream>>>(stats, gnw + l*C_DIM, gnb + l*C_DIM, gna + l*C_DIM, gncoef, N);
    k_gn_apply<<<(N*32 + 255)/256, 256, 0, stream>>>(xc, gncoef, g, N*32);
    k_agg<<<(N + 3)/4, 256, 0, stream>>>(g, rp, csrc, tpt, l, U, N);
    k_gemm1<<<gmw, 256, 0, stream>>>(U, W1t + (size_t)l*C_DIM*H_DIM, b1 + l*H_DIM, h1, stats + 256, N);
    k_ln_coef<<<1, 256, 0, stream>>>(stats + 256, lnw + l*H_DIM, lnb + l*H_DIM, lncoef, N);
    k_gemm2<<<gmw, 256, 0, stream>>>(h1, lncoef, W2t + (size_t)l*C_DIM*H_DIM, b2 + l*C_DIM, xc, N);
  }
  k_final<<<(N + 3)/4, 256, 0, stream>>>(xc, linw, linb, out, N);
}

// Round 2
// 709.693 us; speedup vs baseline: 1.4842x; 1.4842x over previous
//
#include <hip/hip_runtime.h>

#define C_DIM 128
#define H_DIM 256
#define L_NUM 4

typedef __attribute__((ext_vector_type(8))) short bf16x8;
typedef __attribute__((ext_vector_type(4))) float f32x4;

__device__ __forceinline__ unsigned short f2bf(float f){
  unsigned u = __builtin_bit_cast(unsigned, f);
  u = u + 0x7FFFu + ((u >> 16) & 1u);   // round-to-nearest-even
  return (unsigned short)(u >> 16);
}
__device__ __forceinline__ float bf2f(unsigned short b){
  return __builtin_bit_cast(float, ((unsigned)b) << 16);
}

// ---------------- CSR build ----------------
__global__ void k_hist(const int* __restrict__ dst, int* __restrict__ cnt, int E){
  for (int e = blockIdx.x*blockDim.x + threadIdx.x; e < E; e += gridDim.x*blockDim.x)
    atomicAdd(cnt + dst[e], 1);
}

__global__ void k_scan_local(const int* __restrict__ cnt, int* __restrict__ rp,
                             int* __restrict__ bsum, int N){
  __shared__ int tmp[256];
  int t = threadIdx.x; int i = blockIdx.x*256 + t;
  int v = (i < N) ? cnt[i] : 0;
  tmp[t] = v; __syncthreads();
  for (int off = 1; off < 256; off <<= 1){
    int x = (t >= off) ? tmp[t-off] : 0; __syncthreads();
    tmp[t] += x; __syncthreads();
  }
  if (i < N) rp[i] = tmp[t] - v;              // exclusive within block
  if (t == 255) bsum[blockIdx.x] = tmp[t];
}

__global__ void k_scan_bsums(const int* __restrict__ bsum, int* __restrict__ boff, int nb){
  __shared__ int tmp[256];
  int t = threadIdx.x;
  int v = (t < nb) ? bsum[t] : 0;
  tmp[t] = v; __syncthreads();
  for (int off = 1; off < 256; off <<= 1){
    int x = (t >= off) ? tmp[t-off] : 0; __syncthreads();
    tmp[t] += x; __syncthreads();
  }
  if (t < nb) boff[t] = tmp[t] - v;           // exclusive
}

__global__ void k_scan_add(int* __restrict__ rp, const int* __restrict__ boff, int N, int E){
  int i = blockIdx.x*256 + threadIdx.x;
  if (i < N) rp[i] += boff[blockIdx.x];
  if (i == 0) rp[N] = E;
}

__global__ void k_scatter(const int* __restrict__ src, const int* __restrict__ dst,
                          const int* __restrict__ rp, int* __restrict__ cnt,
                          int* __restrict__ csrc, int E){
  for (int e = blockIdx.x*blockDim.x + threadIdx.x; e < E; e += gridDim.x*blockDim.x){
    int d = dst[e];
    int pos = rp[d] + atomicAdd(cnt + d, 1);
    csrc[pos] = src[e];
  }
}

// ---------------- weight transpose+convert ----------------
__global__ void k_wconv(const float* __restrict__ W1, const float* __restrict__ W2,
                        unsigned short* __restrict__ W1t, unsigned short* __restrict__ W2t){
  int i = blockIdx.x*blockDim.x + threadIdx.x;
  if (i >= L_NUM*C_DIM*H_DIM) return;
  int l = i >> 15, r = i & 32767;
  { int k = r >> 8, n = r & 255;  W1t[l*32768 + n*128 + k] = f2bf(W1[i]); }
  { int k = r >> 7, n = r & 127;  W2t[l*32768 + n*256 + k] = f2bf(W2[i]); }
}

// ---------------- graph norm stats ----------------
__global__ void k_gn_reduce(const float* __restrict__ X, float* __restrict__ st, int N){
  int t = threadIdx.x; int c = t & 127; int half = t >> 7;
  float s = 0.f, s2 = 0.f;
  for (int r = blockIdx.x*2 + half; r < N; r += gridDim.x*2){
    float v = X[r*C_DIM + c]; s += v; s2 += v*v;
  }
  __shared__ float a1[256], a2[256];
  a1[t] = s; a2[t] = s2; __syncthreads();
  if (t < 128){
    atomicAdd(st + c, a1[t] + a1[t+128]);
    atomicAdd(st + 128 + c, a2[t] + a2[t+128]);
  }
}

__global__ void k_gn_coef(const float* __restrict__ st, const float* __restrict__ gw,
                          const float* __restrict__ gb, const float* __restrict__ ga,
                          float* __restrict__ coef, int N){
  int c = threadIdx.x;
  if (c >= 128) return;
  float inv = 1.f/(float)N;
  float mean = st[c]*inv;
  float am = ga[c]*mean;
  float var = st[128+c]*inv - 2.f*am*mean + am*am;   // E[(x - a*mean)^2]
  float scale = gw[c] * rsqrtf(var + 1e-5f);
  coef[c] = scale;
  coef[128+c] = gb[c] - scale*am;
}

// ---------------- softmax aggregation, graph_norm+relu fused ----------------
// g(row) = max(A*x+B, 0); assumes t > 0 so z = t*(g+eps) > 0 (init max = 0 safe)
__global__ void k_agg(const float* __restrict__ X, const float* __restrict__ coef,
                      const int* __restrict__ rp, const int* __restrict__ csrc,
                      const float* __restrict__ tptr, int l,
                      unsigned short* __restrict__ U, int N){
  int wave = threadIdx.x >> 6, lane = threadIdx.x & 63;
  int n = blockIdx.x*4 + wave;
  if (n >= N) return;
  float tv = tptr[l];
  int c = lane*2;
  float2 A = *(const float2*)(coef + c);
  float2 B = *(const float2*)(coef + 128 + c);
  int jb = rp[n], je = rp[n+1];
  float m0 = 0.f, m1 = 0.f, d0 = 0.f, d1 = 0.f, s0 = 0.f, s1 = 0.f;
  for (int j = jb; j < je; ++j){
    int sidx = csrc[j];
    float2 v = *(const float2*)(X + sidx*C_DIM + c);
    float msg0 = fmaxf(A.x*v.x + B.x, 0.f) + 1e-7f;
    float msg1 = fmaxf(A.y*v.y + B.y, 0.f) + 1e-7f;
    float z0 = tv*msg0, z1 = tv*msg1;
    float nm0 = fmaxf(m0, z0), nm1 = fmaxf(m1, z1);
    float e0 = __expf(z0 - nm0), r0 = __expf(m0 - nm0);
    float e1 = __expf(z1 - nm1), r1 = __expf(m1 - nm1);
    d0 = d0*r0 + e0;            d1 = d1*r1 + e1;
    s0 = s0*r0 + msg0*e0;       s1 = s1*r1 + msg1*e1;
    m0 = nm0; m1 = nm1;
  }
  float2 xo = *(const float2*)(X + n*C_DIM + c);
  float g0 = fmaxf(A.x*xo.x + B.x, 0.f);
  float g1 = fmaxf(A.y*xo.y + B.y, 0.f);
  float u0 = s0/(d0 + 1e-16f) + g0;
  float u1 = s1/(d1 + 1e-16f) + g1;
  unsigned pk = (unsigned)f2bf(u0) | ((unsigned)f2bf(u1) << 16);
  *(unsigned*)(U + n*C_DIM + c) = pk;
}

// ---------------- GEMM1: h1(bf16) = U(bf16)[M,128] @ W1t^T + b1 ; per-block LN partials ----------------
__global__ void k_gemm1(const unsigned short* __restrict__ A, const unsigned short* __restrict__ Bt,
                        const float* __restrict__ b1, unsigned short* __restrict__ H1,
                        float* __restrict__ part, int M){
  __shared__ __align__(16) char smem[64*256];   // 64 rows x 128 bf16 (256B rows), swizzled
  __shared__ float rbuf[8];
  const int tid = threadIdx.x;
  const int m0 = blockIdx.x * 64;
  const int wave = tid >> 6, lane = tid & 63;
  const int lr = lane & 15, lc = lane >> 4;

  bf16x8 bf[4][4];
  #pragma unroll
  for (int nf = 0; nf < 4; ++nf){
    int n = wave*64 + nf*16 + lr;
    #pragma unroll
    for (int ks = 0; ks < 4; ++ks)
      bf[nf][ks] = *(const bf16x8*)(Bt + n*128 + ks*32 + lc*8);
  }
  #pragma unroll
  for (int p = 0; p < 4; ++p){
    int idx = p*256 + tid;
    int row = idx >> 4, ch = idx & 15;
    int r = m0 + row;
    uint4 v = make_uint4(0u,0u,0u,0u);
    if (r < M) v = *(const uint4*)(A + r*128 + ch*8);
    int o = (row*256 + ch*16) ^ ((row & 7) << 4);
    *(uint4*)(smem + o) = v;
  }
  __syncthreads();

  f32x4 acc[4][4] = {};
  #pragma unroll
  for (int ks = 0; ks < 4; ++ks){
    bf16x8 a[4];
    #pragma unroll
    for (int mf = 0; mf < 4; ++mf){
      int row = mf*16 + lr;
      int o = (row*256 + ks*64 + lc*16) ^ ((row & 7) << 4);
      a[mf] = *(const bf16x8*)(smem + o);
    }
    #pragma unroll
    for (int mf = 0; mf < 4; ++mf)
      #pragma unroll
      for (int nf = 0; nf < 4; ++nf)
        acc[mf][nf] = __builtin_amdgcn_mfma_f32_16x16x32_bf16(a[mf], bf[nf][ks], acc[mf][nf], 0, 0, 0);
  }

  float s1 = 0.f, s2 = 0.f;
  #pragma unroll
  for (int mf = 0; mf < 4; ++mf){
    #pragma unroll
    for (int j = 0; j < 4; ++j){
      int r = m0 + mf*16 + lc*4 + j;
      if (r < M){
        #pragma unroll
        for (int nf = 0; nf < 4; ++nf){
          int col = wave*64 + nf*16 + lr;
          float v = acc[mf][nf][j] + b1[col];
          H1[r*H_DIM + col] = f2bf(v);
          s1 += v; s2 += v*v;
        }
      }
    }
  }
  #pragma unroll
  for (int o = 32; o; o >>= 1){ s1 += __shfl_down(s1, o); s2 += __shfl_down(s2, o); }
  if (lane == 0){ rbuf[wave] = s1; rbuf[4 + wave] = s2; }
  __syncthreads();
  if (tid == 0)
    part[blockIdx.x*2]     = rbuf[0]+rbuf[1]+rbuf[2]+rbuf[3];
  if (tid == 1)
    part[blockIdx.x*2 + 1] = rbuf[4]+rbuf[5]+rbuf[6]+rbuf[7];
}

__global__ void k_ln_coef(const float* __restrict__ part, int nb,
                          const float* __restrict__ lnw, const float* __restrict__ lnb,
                          float* __restrict__ coef, int M){
  __shared__ float s1s[256], s2s[256];
  int t = threadIdx.x;
  float s1 = 0.f, s2 = 0.f;
  for (int i = t; i < nb; i += 256){ s1 += part[2*i]; s2 += part[2*i+1]; }
  s1s[t] = s1; s2s[t] = s2; __syncthreads();
  for (int off = 128; off; off >>= 1){
    if (t < off){ s1s[t] += s1s[t+off]; s2s[t] += s2s[t+off]; }
    __syncthreads();
  }
  double NH = (double)M * (double)H_DIM;
  double mean = (double)s1s[0] / NH;
  double var = (double)s2s[0] / NH - mean*mean;
  double sd = sqrt(var > 0.0 ? var : 0.0);
  float denom = (float)sd + 1e-5f;
  float wv = lnw[t] / denom;
  coef[t] = wv;
  coef[256 + t] = lnb[t] - (float)mean * wv;
}

// ---------------- GEMM2: x += relu(affine(H1))(bf16) @ W2t^T + b2 ----------------
__global__ void k_gemm2(const unsigned short* __restrict__ H1, const float* __restrict__ lncoef,
                        const unsigned short* __restrict__ Bt, const float* __restrict__ b2,
                        float* __restrict__ X, int M){
  __shared__ __align__(16) char smem[64*512];   // 64 rows x 256 bf16 (512B rows), swizzled
  const int tid = threadIdx.x;
  const int m0 = blockIdx.x * 64;
  const int wave = tid >> 6, lane = tid & 63;
  const int lr = lane & 15, lc = lane >> 4;
  const float* colw = lncoef;
  const float* colb = lncoef + 256;

  bf16x8 bf[2][8];
  #pragma unroll
  for (int nf = 0; nf < 2; ++nf){
    int n = wave*32 + nf*16 + lr;
    #pragma unroll
    for (int ks = 0; ks < 8; ++ks)
      bf[nf][ks] = *(const bf16x8*)(Bt + n*256 + ks*32 + lc*8);
  }
  #pragma unroll
  for (int p = 0; p < 8; ++p){
    int idx = (p*256 + tid)*8;
    int row = idx >> 8, col = idx & 255;
    int r = m0 + row;
    uint4 v = make_uint4(0u,0u,0u,0u);
    if (r < M) v = *(const uint4*)(H1 + r*H_DIM + col);
    unsigned short hb[8] = {(unsigned short)(v.x&0xffff),(unsigned short)(v.x>>16),
                            (unsigned short)(v.y&0xffff),(unsigned short)(v.y>>16),
                            (unsigned short)(v.z&0xffff),(unsigned short)(v.z>>16),
                            (unsigned short)(v.w&0xffff),(unsigned short)(v.w>>16)};
    unsigned out[4];
    #pragma unroll
    for (int q = 0; q < 4; ++q){
      float f0 = fmaxf(colw[col+2*q]  *bf2f(hb[2*q])   + colb[col+2*q],   0.f);
      float f1 = fmaxf(colw[col+2*q+1]*bf2f(hb[2*q+1]) + colb[col+2*q+1], 0.f);
      out[q] = (unsigned)f2bf(f0) | ((unsigned)f2bf(f1) << 16);
    }
    int o = (row*512 + col*2) ^ ((row & 7) << 4);
    *(uint4*)(smem + o) = make_uint4(out[0],out[1],out[2],out[3]);
  }
  __syncthreads();

  f32x4 acc[4][2] = {};
  #pragma unroll
  for (int ks = 0; ks < 8; ++ks){
    bf16x8 a[4];
    #pragma unroll
    for (int mf = 0; mf < 4; ++mf){
      int row = mf*16 + lr;
      int o = (row*512 + ks*64 + lc*16) ^ ((row & 7) << 4);
      a[mf] = *(const bf16x8*)(smem + o);
    }
    #pragma unroll
    for (int mf = 0; mf < 4; ++mf)
      #pragma unroll
      for (int nf = 0; nf < 2; ++nf)
        acc[mf][nf] = __builtin_amdgcn_mfma_f32_16x16x32_bf16(a[mf], bf[nf][ks], acc[mf][nf], 0, 0, 0);
  }
  #pragma unroll
  for (int mf = 0; mf < 4; ++mf){
    #pragma unroll
    for (int j = 0; j < 4; ++j){
      int r = m0 + mf*16 + lc*4 + j;
      if (r < M){
        #pragma unroll
        for (int nf = 0; nf < 2; ++nf){
          int col = wave*32 + nf*16 + lr;
          X[r*C_DIM + col] += acc[mf][nf][j] + b2[col];
        }
      }
    }
  }
}

// ---------------- final linear ----------------
__global__ void k_final(const float* __restrict__ X, const float* __restrict__ lw,
                        const float* __restrict__ lb, float* __restrict__ out, int N){
  int wave = threadIdx.x >> 6, lane = threadIdx.x & 63;
  int n = blockIdx.x*4 + wave;
  if (n >= N) return;
  float2 v = *(const float2*)(X + n*C_DIM + lane*2);
  float2 w = *(const float2*)(lw + lane*2);
  float s = v.x*w.x + v.y*w.y;
  #pragma unroll
  for (int o = 32; o; o >>= 1) s += __shfl_down(s, o);
  if (lane == 0) out[n] = s + lb[0];
}

extern "C" void kernel_launch(void* const* d_in, const int* in_sizes, int n_in,
                              void* d_out, int out_size, void* d_ws, size_t ws_size,
                              hipStream_t stream){
  const float* x    = (const float*)d_in[0];
  const int*   src  = (const int*)d_in[1];
  const int*   dst  = (const int*)d_in[2];
  const float* W1   = (const float*)d_in[3];
  const float* b1   = (const float*)d_in[4];
  const float* lnw  = (const float*)d_in[5];
  const float* lnb  = (const float*)d_in[6];
  const float* W2   = (const float*)d_in[7];
  const float* b2   = (const float*)d_in[8];
  const float* tpt  = (const float*)d_in[9];
  const float* gnw  = (const float*)d_in[10];
  const float* gnb  = (const float*)d_in[11];
  const float* gna  = (const float*)d_in[12];
  const float* linw = (const float*)d_in[13];
  const float* linb = (const float*)d_in[14];
  (void)n_in; (void)out_size; (void)ws_size;
  const int N = in_sizes[0] / C_DIM;
  const int E = in_sizes[1];
  float* out = (float*)d_out;

  const int gmw = (N + 63)/64;

  char* wsp = (char*)d_ws; size_t off = 0;
  auto alloc = [&](size_t b)->char*{ char* p = wsp + off; off += (b + 255) & ~(size_t)255; return p; };
  int* cnt          = (int*)alloc((size_t)N*4);
  int* rp           = (int*)alloc((size_t)(N+1)*4);
  int* bsum         = (int*)alloc(1024);
  int* boff         = (int*)alloc(1024);
  float* stats      = (float*)alloc(1024);   // chsum[128], chsumsq[128]
  float* gncoef     = (float*)alloc(1024);
  float* lncoef     = (float*)alloc(2048);
  float* lnpart     = (float*)alloc((size_t)gmw*2*4);
  int* csrc         = (int*)alloc((size_t)E*4);
  unsigned short* W1t = (unsigned short*)alloc((size_t)L_NUM*C_DIM*H_DIM*2);
  unsigned short* W2t = (unsigned short*)alloc((size_t)L_NUM*C_DIM*H_DIM*2);
  unsigned short* U = (unsigned short*)alloc((size_t)N*C_DIM*2);
  unsigned short* h1 = (unsigned short*)alloc((size_t)N*H_DIM*2);
  float* xc         = (float*)alloc((size_t)N*C_DIM*4);

  const int SB = (N + 255)/256;
  hipMemsetAsync(cnt, 0, (size_t)N*4, stream);
  k_hist<<<1024, 256, 0, stream>>>(dst, cnt, E);
  k_scan_local<<<SB, 256, 0, stream>>>(cnt, rp, bsum, N);
  k_scan_bsums<<<1, 256, 0, stream>>>(bsum, boff, SB);
  k_scan_add<<<SB, 256, 0, stream>>>(rp, boff, N, E);
  hipMemsetAsync(cnt, 0, (size_t)N*4, stream);
  k_scatter<<<1024, 256, 0, stream>>>(src, dst, rp, cnt, csrc, E);
  k_wconv<<<(L_NUM*C_DIM*H_DIM + 255)/256, 256, 0, stream>>>(W1, W2, W1t, W2t);
  hipMemcpyAsync(xc, x, (size_t)N*C_DIM*4, hipMemcpyDeviceToDevice, stream);

  for (int l = 0; l < L_NUM; ++l){
    hipMemsetAsync(stats, 0, 1024, stream);
    k_gn_reduce<<<256, 256, 0, stream>>>(xc, stats, N);
    k_gn_coef<<<1, 128, 0, stream>>>(stats, gnw + l*C_DIM, gnb + l*C_DIM, gna + l*C_DIM, gncoef, N);
    k_agg<<<(N + 3)/4, 256, 0, stream>>>(xc, gncoef, rp, csrc, tpt, l, U, N);
    k_gemm1<<<gmw, 256, 0, stream>>>(U, W1t + (size_t)l*C_DIM*H_DIM, b1 + l*H_DIM, h1, lnpart, N);
    k_ln_coef<<<1, 256, 0, stream>>>(lnpart, gmw, lnw + l*H_DIM, lnb + l*H_DIM, lncoef, N);
    k_gemm2<<<gmw, 256, 0, stream>>>(h1, lncoef, W2t + (size_t)l*C_DIM*H_DIM, b2 + l*C_DIM, xc, N);
  }
  k_final<<<(N + 3)/4, 256, 0, stream>>>(xc, linw, linb, out, N);
}